// Round 5
// baseline (602.309 us; speedup 1.0000x reference)
//
#include <hip/hip_runtime.h>
#include <hip/hip_bf16.h>
#include <hip/hip_fp16.h>
#include <cstdint>
#include <cstddef>

#define H    50
#define G4   200      // 4*H gates
#define TT   256      // timesteps
#define BATCH 512
#define KDIM 144      // layer-0 input dim
#define ODIM 144      // FC output dim
#define XPLD 208      // XP row width: gate-interleaved p = kk*4+gate, kk padded to 52
#define WKP  160      // padded K for the xproj weight panel

typedef _Float16 half8  __attribute__((ext_vector_type(8)));
typedef _Float16 half4v __attribute__((ext_vector_type(4)));
typedef float    floatx4 __attribute__((ext_vector_type(4)));

__device__ __forceinline__ float sigm(float x) {
    return 1.0f / (1.0f + __expf(-x));
}
__device__ __forceinline__ float tanhx(float x) {
    float e = __expf(2.0f * x);
    return 1.0f - 2.0f / (e + 1.0f);
}

// ---------- Kernel 0: convert W_ih0 [200][144] fp32 -> Wf [208][160] f16, rows
// permuted to p = kk*4 + gate (so XP columns come out gate-interleaved). ----------
__global__ __launch_bounds__(256) void wcvt(const float* __restrict__ W,
                                            _Float16* __restrict__ Wf) {
    const int idx = blockIdx.x * 256 + threadIdx.x;
    if (idx >= XPLD * WKP) return;
    const int p = idx / WKP, k = idx % WKP;
    const int kk = p >> 2, g = p & 3;
    const float v = (kk < H && k < KDIM) ? W[(size_t)(g * H + kk) * KDIM + k] : 0.0f;
    Wf[idx] = (_Float16)v;
}

// ---------- Kernel 1: XP[m][208] (f16) = X[m][144] @ Wf^T, MFMA, no LDS ----------
// 2048 WGs x 256 thr; wave w handles m-tile of 16 rows x all 13 n-tiles x 5 ksteps.
// A-frag straight from global X fp32 (cvt in-reg); B-frag from Wf f16 (L2-resident).
__global__ __launch_bounds__(256) void xproj(const float* __restrict__ X,
                                             const _Float16* __restrict__ Wf,
                                             _Float16* __restrict__ XP) {
    const int lane = threadIdx.x & 63;
    const int wv   = threadIdx.x >> 6;
    const int mrow = lane & 15;
    const int q    = lane >> 4;
    const int m0   = blockIdx.x * 64 + wv * 16;

    floatx4 acc[13];
    #pragma unroll
    for (int n = 0; n < 13; ++n) acc[n] = (floatx4)(0.0f);

    #pragma unroll
    for (int s = 0; s < 5; ++s) {
        const int kbase = s * 32 + q * 8;
        half8 a;
        if (kbase + 7 < KDIM) {
            const float4 x0 = *(const float4*)&X[(size_t)(m0 + mrow) * KDIM + kbase];
            const float4 x1 = *(const float4*)&X[(size_t)(m0 + mrow) * KDIM + kbase + 4];
            a[0] = (_Float16)x0.x; a[1] = (_Float16)x0.y;
            a[2] = (_Float16)x0.z; a[3] = (_Float16)x0.w;
            a[4] = (_Float16)x1.x; a[5] = (_Float16)x1.y;
            a[6] = (_Float16)x1.z; a[7] = (_Float16)x1.w;
        } else {
            #pragma unroll
            for (int j = 0; j < 8; ++j) a[j] = (_Float16)0.0f;
        }
        #pragma unroll
        for (int n = 0; n < 13; ++n) {
            const half8 b = *(const half8*)&Wf[(size_t)(n * 16 + mrow) * WKP + s * 32 + q * 8];
            acc[n] = __builtin_amdgcn_mfma_f32_16x16x32_f16(a, b, acc[n], 0, 0, 0);
        }
    }
    // C layout: col = lane&15, row = q*4 + reg
    #pragma unroll
    for (int n = 0; n < 13; ++n) {
        #pragma unroll
        for (int r = 0; r < 4; ++r) {
            XP[(size_t)(m0 + q * 4 + r) * XPLD + n * 16 + mrow] = (_Float16)acc[n][r];
        }
    }
}

// ---------- Kernel 2: MFMA recurrence, in-register epilogue, 1 barrier/step ------
// 128 WGs x 512 thr, 4 batch rows/WG (B cols 0..3; cols 4..15 stay zero).
// Unified row space (512 rows): rows [0,256) = L0 gates (p = kk*4+gate, kk<64 pad),
// rows [256,512) = L1 gates. K = 128 padded: k 0..49 = h0, 50..99 = h1.
// Wave w owns L0 tiles {2w,2w+1} (ksteps 0,1) and L1 tiles {2w,2w+1} (ksteps 0..3).
// A-frags resident f16 (built once). B double-buffered in LDS, layout
// [buf][s][q][col][j] -> hot read is addr = lane*16: coalesced, conflict-free.
// C regs ARE the 4 gates of one hidden unit -> activations in-register.
// L1 lags one step: at step t compute gates0(t) and gates1(t-1).
__global__ __launch_bounds__(512, 2) void lstm_mfma(
    const _Float16* __restrict__ XP,
    const float* __restrict__ Whh0,
    const float* __restrict__ Wih1,
    const float* __restrict__ Whh1,
    const float* __restrict__ bih0, const float* __restrict__ bhh0,
    const float* __restrict__ bih1, const float* __restrict__ bhh1,
    const float* __restrict__ Wfc,  const float* __restrict__ bfc,
    float* __restrict__ out)
{
    const int b0   = blockIdx.x * 4;
    const int tid  = threadIdx.x;
    const int lane = tid & 63;
    const int w    = tid >> 6;       // wave 0..7
    const int col  = lane & 15;      // B col / C col (batch row for col<4)
    const int q    = lane >> 4;      // 0..3

    __shared__ _Float16 B2[2][4][4][16][8];   // [buf][kstep][q][col][j]
    __shared__ float h1f[4][52];

    // ---- build resident A-frags (once). A mapping: m = lane&15, k = q*8+j ----
    const int prow = lane & 15;                       // row within tile
    half8 A0[2][2], A1[2][4];
    #pragma unroll
    for (int tl = 0; tl < 2; ++tl) {
        const int kkA  = 8 * w + 4 * tl + (prow >> 2);
        const int gate = prow & 3;
        const float* r0 = Whh0 + (size_t)(gate * H + (kkA < H ? kkA : 0)) * H;
        const float* r1i = Wih1 + (size_t)(gate * H + (kkA < H ? kkA : 0)) * H;
        const float* r1h = Whh1 + (size_t)(gate * H + (kkA < H ? kkA : 0)) * H;
        #pragma unroll
        for (int s = 0; s < 2; ++s) {
            #pragma unroll
            for (int j = 0; j < 8; ++j) {
                const int k = s * 32 + q * 8 + j;
                A0[tl][s][j] = (_Float16)((kkA < H && k < H) ? r0[k] : 0.0f);
            }
        }
        #pragma unroll
        for (int s = 0; s < 4; ++s) {
            #pragma unroll
            for (int j = 0; j < 8; ++j) {
                const int k = s * 32 + q * 8 + j;
                float v = 0.0f;
                if (kkA < H) {
                    if (k < H)            v = r1i[k];
                    else if (k < 2 * H)   v = r1h[k - H];
                }
                A1[tl][s][j] = (_Float16)v;
            }
        }
    }
    // ---- per-lane stage-B state. C mapping: col = lane&15, kk = 8w+4tl+q ----
    float4 bs0[2], bs1[2];
    float  c0[2] = {0.0f, 0.0f}, c1[2] = {0.0f, 0.0f};
    #pragma unroll
    for (int tl = 0; tl < 2; ++tl) {
        const int kkB = 8 * w + 4 * tl + q;
        const int kc  = (kkB < H) ? kkB : 0;
        bs0[tl] = make_float4(bih0[kc] + bhh0[kc],
                              bih0[H + kc] + bhh0[H + kc],
                              bih0[2*H + kc] + bhh0[2*H + kc],
                              bih0[3*H + kc] + bhh0[3*H + kc]);
        bs1[tl] = make_float4(bih1[kc] + bhh1[kc],
                              bih1[H + kc] + bhh1[H + kc],
                              bih1[2*H + kc] + bhh1[2*H + kc],
                              bih1[3*H + kc] + bhh1[3*H + kc]);
    }
    // ---- zero both B buffers (k>=100 and cols>=4 stay zero forever) ----
    for (int i = tid; i < 2 * 4 * 4 * 16 * 8; i += 512) ((_Float16*)B2)[i] = (_Float16)0.0f;

    // xp prefetch for t=0
    half4v xc[2], xn[2];
    #pragma unroll
    for (int tl = 0; tl < 2; ++tl) {
        const int kkB = 8 * w + 4 * tl + q;
        half4v z = {(_Float16)0.f, (_Float16)0.f, (_Float16)0.f, (_Float16)0.f};
        xc[tl] = z;
        if (kkB < H && col < 4)
            xc[tl] = *(const half4v*)&XP[((size_t)(b0 + col) * TT + 0) * XPLD + 4 * kkB];
    }
    __syncthreads();

    for (int t = 0; t < TT; ++t) {
        const int rb = t & 1, wb = rb ^ 1;
        // B-frag reads: addr = lane*16 within [rb][s] -> coalesced
        half8 bf[4];
        #pragma unroll
        for (int s = 0; s < 4; ++s) bf[s] = *(const half8*)&B2[rb][s][q][col][0];
        // prefetch xp(t+1)
        #pragma unroll
        for (int tl = 0; tl < 2; ++tl) {
            const int kkB = 8 * w + 4 * tl + q;
            half4v z = {(_Float16)0.f, (_Float16)0.f, (_Float16)0.f, (_Float16)0.f};
            xn[tl] = z;
            if (t + 1 < TT && kkB < H && col < 4)
                xn[tl] = *(const half4v*)&XP[((size_t)(b0 + col) * TT + (t + 1)) * XPLD + 4 * kkB];
        }
        // MFMA: gates0(t) and gates1(t-1)
        floatx4 acc0[2], acc1[2];
        #pragma unroll
        for (int tl = 0; tl < 2; ++tl) { acc0[tl] = (floatx4)(0.0f); acc1[tl] = (floatx4)(0.0f); }
        #pragma unroll
        for (int tl = 0; tl < 2; ++tl) {
            #pragma unroll
            for (int s = 0; s < 2; ++s)
                acc0[tl] = __builtin_amdgcn_mfma_f32_16x16x32_f16(A0[tl][s], bf[s], acc0[tl], 0, 0, 0);
            #pragma unroll
            for (int s = 0; s < 4; ++s)
                acc1[tl] = __builtin_amdgcn_mfma_f32_16x16x32_f16(A1[tl][s], bf[s], acc1[tl], 0, 0, 0);
        }
        // stage B (in-register): L0 -> h0(t); L1 -> h1(t-1) (skip at t==0)
        #pragma unroll
        for (int tl = 0; tl < 2; ++tl) {
            const int kkB = 8 * w + 4 * tl + q;
            if (kkB < H) {
                {
                    const float gi = sigm(acc0[tl][0] + bs0[tl].x + (float)xc[tl][0]);
                    const float gf = sigm(acc0[tl][1] + bs0[tl].y + (float)xc[tl][1]);
                    const float gg = tanhx(acc0[tl][2] + bs0[tl].z + (float)xc[tl][2]);
                    const float go = sigm(acc0[tl][3] + bs0[tl].w + (float)xc[tl][3]);
                    c0[tl] = gf * c0[tl] + gi * gg;
                    const float hv = go * tanhx(c0[tl]);
                    if (col < 4) B2[wb][kkB >> 5][(kkB >> 3) & 3][col][kkB & 7] = (_Float16)hv;
                }
                if (t > 0) {
                    const float qi = sigm(acc1[tl][0] + bs1[tl].x);
                    const float qf = sigm(acc1[tl][1] + bs1[tl].y);
                    const float qg = tanhx(acc1[tl][2] + bs1[tl].z);
                    const float qo = sigm(acc1[tl][3] + bs1[tl].w);
                    c1[tl] = qf * c1[tl] + qi * qg;
                    const float hv = qo * tanhx(c1[tl]);
                    const int k1 = H + kkB;
                    if (col < 4) B2[wb][k1 >> 5][(k1 >> 3) & 3][col][k1 & 7] = (_Float16)hv;
                }
            }
        }
        xc[0] = xn[0]; xc[1] = xn[1];
        __syncthreads();
    }
    // ---- tail: gates1(TT-1) from buf[TT&1] = [h0(TT-1); h1(TT-2)] ----
    {
        const int rb = TT & 1;
        half8 bf[4];
        #pragma unroll
        for (int s = 0; s < 4; ++s) bf[s] = *(const half8*)&B2[rb][s][q][col][0];
        #pragma unroll
        for (int tl = 0; tl < 2; ++tl) {
            floatx4 a1 = (floatx4)(0.0f);
            #pragma unroll
            for (int s = 0; s < 4; ++s)
                a1 = __builtin_amdgcn_mfma_f32_16x16x32_f16(A1[tl][s], bf[s], a1, 0, 0, 0);
            const int kkB = 8 * w + 4 * tl + q;
            if (kkB < H && col < 4) {
                const float qi = sigm(a1[0] + bs1[tl].x);
                const float qf = sigm(a1[1] + bs1[tl].y);
                const float qg = tanhx(a1[2] + bs1[tl].z);
                const float qo = sigm(a1[3] + bs1[tl].w);
                c1[tl] = qf * c1[tl] + qi * qg;
                h1f[col][kkB] = qo * tanhx(c1[tl]);
            }
        }
        __syncthreads();
    }
    // ---- fused FC on h1(TT-1): 4 rows x 144 outs ----
    for (int idx = tid; idx < 4 * ODIM; idx += 512) {
        const int cc = idx / ODIM, o = idx - cc * ODIM;
        float s = bfc[o];
        const float* wr = Wfc + (size_t)o * H;
        #pragma unroll
        for (int k = 0; k < H; ++k) s += wr[k] * h1f[cc][k];
        out[(size_t)(b0 + cc) * ODIM + o] = s;
    }
}

extern "C" void kernel_launch(void* const* d_in, const int* in_sizes, int n_in,
                              void* d_out, int out_size, void* d_ws, size_t ws_size,
                              hipStream_t stream) {
    const float* x    = (const float*)d_in[0];
    const float* wih0 = (const float*)d_in[1];
    const float* whh0 = (const float*)d_in[2];
    const float* bih0 = (const float*)d_in[3];
    const float* bhh0 = (const float*)d_in[4];
    const float* wih1 = (const float*)d_in[5];
    const float* whh1 = (const float*)d_in[6];
    const float* bih1 = (const float*)d_in[7];
    const float* bhh1 = (const float*)d_in[8];
    const float* wfc  = (const float*)d_in[9];
    const float* bfc  = (const float*)d_in[10];
    float* outp = (float*)d_out;

    _Float16* XP = (_Float16*)d_ws;                           // 131072*208*2 = 54.5 MB
    _Float16* Wf = (_Float16*)((char*)d_ws + (size_t)131072 * XPLD * 2);  // 66.5 KB

    wcvt<<<(XPLD * WKP + 255) / 256, 256, 0, stream>>>(wih0, Wf);
    xproj<<<BATCH * TT / 64, 256, 0, stream>>>(x, Wf, XP);
    lstm_mfma<<<BATCH / 4, 512, 0, stream>>>(XP, whh0, wih1, whh1,
                                             bih0, bhh0, bih1, bhh1,
                                             wfc, bfc, outp);
}